// Round 14
// baseline (49.804 us; speedup 1.0000x reference)
//
#include <hip/hip_runtime.h>
#include <hip/hip_bf16.h>

typedef __attribute__((ext_vector_type(8))) short bf16x8;
typedef __attribute__((ext_vector_type(4))) float f32x4;
typedef __attribute__((ext_vector_type(4))) int i32x4;

#define LOG2E 1.4426950408889634f

static __device__ __forceinline__ unsigned int f2bfu(float f) {
    return (unsigned int)__builtin_bit_cast(unsigned short, __float2bfloat16(f));
}
static __device__ __forceinline__ unsigned int pack2(float lo, float hi) {
    return (f2bfu(hi) << 16) | f2bfu(lo);
}
static __device__ __forceinline__ unsigned short f2bf(float f) {
    return __builtin_bit_cast(unsigned short, __float2bfloat16(f));
}

// ---------------- W prep: emit Wt in proj-staging-linear order, bf16 ----------
__global__ __launch_bounds__(256) void wtrans_kernel(
    const float* __restrict__ Wq, const float* __restrict__ Wk,
    const float* __restrict__ Wv, unsigned short* __restrict__ Wts)
{
    const int part = blockIdx.x;             // 0..5
    const int t    = blockIdx.y;             // 0..15
    const int c    = part * 256 + threadIdx.x;
    const int n    = c >> 3;
    const int mat  = n >> 6;
    const int nl   = n & 63;
    const int k0   = t * 64 + (c & 7) * 8;
    const float* W = (mat == 0) ? Wq : ((mat == 1) ? Wk : Wv);
    const float scale = (mat == 0) ? 0.03125f : 1.0f;
    unsigned int s[8];
#pragma unroll
    for (int j = 0; j < 8; ++j)
        s[j] = (unsigned int)f2bf(W[(size_t)(k0 + j) * 64 + nl] * scale);
    i32x4 pk;
    pk[0] = (int)(s[0] | (s[1] << 16));
    pk[1] = (int)(s[2] | (s[3] << 16));
    pk[2] = (int)(s[4] | (s[5] << 16));
    pk[3] = (int)(s[6] | (s[7] << 16));
    *(i32x4*)(Wts + (size_t)t * 12288 + (size_t)c * 8) = pk;
}

// ---------------- projection: x-prefetch 4 steps deep -------------------------
__global__ __launch_bounds__(256, 2) void proj_kernel(
    const float* __restrict__ x, const unsigned short* __restrict__ Wts,
    unsigned short* __restrict__ Qb, unsigned short* __restrict__ Kb,
    unsigned short* __restrict__ Vt)
{
    __shared__ __align__(16) unsigned short sA[2][32][72];    // [buf][m][k] bf16
    __shared__ __align__(16) unsigned short sB[2][192][72];   // [buf][n][k] bf16
    __shared__ __align__(16) unsigned short sVT[64][40];      // V transpose staging

    const int tid  = threadIdx.x;
    const int w    = tid >> 6;
    const int wm   = w >> 1;
    const int wn   = w & 1;
    const int lane = tid & 63;
    const int r    = lane & 15;
    const int g    = lane >> 4;
    const int mbase = blockIdx.x * 32;

    const int arow = tid >> 3;
    const int acb  = (tid & 7) * 8;
    const float* xptr = x + (size_t)(mbase + arow) * 1024 + acb;

    f32x4 acc[6];
#pragma unroll
    for (int i = 0; i < 6; ++i) acc[i] = (f32x4)0.0f;

    float4 XAa0, XAa1, XAb0, XAb1, XAc0, XAc1, XAd0, XAd1;
    i32x4 BB[6];

#define LOADX(S0, S1, t_) do { \
        const float* xp = xptr + (size_t)(t_) * 64; \
        S0 = *(const float4*)(xp);  S1 = *(const float4*)(xp + 4); \
    } while (0)

#define LOADB(t_) do { \
        const unsigned short* wp = Wts + (size_t)(t_) * 12288 + (size_t)tid * 8; \
        _Pragma("unroll") \
        for (int i = 0; i < 6; ++i) BB[i] = *(const i32x4*)(wp + i * 2048); \
    } while (0)

#define STORESTEP(buf, S0, S1) do { \
        i32x4 pa0 = {(int)pack2(S0.x, S0.y), (int)pack2(S0.z, S0.w), \
                     (int)pack2(S1.x, S1.y), (int)pack2(S1.z, S1.w)}; \
        *(i32x4*)&sA[buf][arow][acb] = pa0; \
        _Pragma("unroll") \
        for (int i = 0; i < 6; ++i) { \
            const int c = tid + 256 * i; \
            *(i32x4*)&sB[buf][c >> 3][(c & 7) * 8] = BB[i]; \
        } \
    } while (0)

#define COMPSTEP(buf) do { \
        _Pragma("unroll") \
        for (int h = 0; h < 2; ++h) { \
            bf16x8 af = *(const bf16x8*)&sA[buf][wm * 16 + r][h * 32 + g * 8]; \
            _Pragma("unroll") \
            for (int nt = 0; nt < 6; ++nt) { \
                bf16x8 bfr = *(const bf16x8*)&sB[buf][(nt * 2 + wn) * 16 + r][h * 32 + g * 8]; \
                acc[nt] = __builtin_amdgcn_mfma_f32_16x16x32_bf16(af, bfr, acc[nt], 0, 0, 0); \
            } \
        } \
    } while (0)

    LOADX(XAa0, XAa1, 0);
    LOADX(XAb0, XAb1, 1);
    LOADX(XAc0, XAc1, 2);
    LOADX(XAd0, XAd1, 3);
    LOADB(0);
#pragma unroll 1
    for (int t = 0; t < 16; t += 4) {
        STORESTEP(0, XAa0, XAa1);
        __syncthreads();
        if (t + 4 < 16) LOADX(XAa0, XAa1, t + 4);
        LOADB(t + 1);
        COMPSTEP(0);

        STORESTEP(1, XAb0, XAb1);
        __syncthreads();
        if (t + 5 < 16) LOADX(XAb0, XAb1, t + 5);
        LOADB(t + 2);
        COMPSTEP(1);

        STORESTEP(0, XAc0, XAc1);
        __syncthreads();
        if (t + 6 < 16) LOADX(XAc0, XAc1, t + 6);
        LOADB(t + 3);
        COMPSTEP(0);

        STORESTEP(1, XAd0, XAd1);
        __syncthreads();
        if (t + 7 < 16) LOADX(XAd0, XAd1, t + 7);
        if (t + 4 < 16) LOADB(t + 4);
        COMPSTEP(1);
    }

    const int row0 = mbase + wm * 16 + g * 4;
#pragma unroll
    for (int nt = 0; nt < 6; ++nt) {
        const int ti  = nt * 2 + wn;
        const int mat = ti >> 2;
        const int col = (ti & 3) * 16 + r;
#pragma unroll
        for (int j = 0; j < 4; ++j) {
            const float v = acc[nt][j];
            if (mat == 0) {
                Qb[(size_t)(row0 + j) * 64 + col] = f2bf(v);
            } else if (mat == 1) {
                Kb[(size_t)(row0 + j) * 64 + col] = f2bf(v);
            } else {
                sVT[col][wm * 16 + g * 4 + j] = f2bf(v);
            }
        }
    }
    __syncthreads();
    {
        const int h = tid >> 2, c = tid & 3;
        const int bb = mbase >> 11, tloc = mbase & 2047;
        unsigned short* dst = Vt + ((size_t)bb * 64 + h) * 2048 + tloc + c * 8;
        *(i32x4*)dst = *(const i32x4*)&sVT[h][c * 8];
    }
}

// ---------------- causal flash attention -------------------------------------
// Balanced QBLK=64 (tiles p and 63-p), 8 waves kv-split mod 8, KV-step 32.
// Cross-iteration K-prefetch (ping-pong K0/K1); V single-buffered (latency
// hides under QK+softmax). All accumulator indices compile-time static.
__global__ __launch_bounds__(512, 2) void attn_kernel(
    const unsigned short* __restrict__ Qb, const unsigned short* __restrict__ Kb,
    const unsigned short* __restrict__ Vt, float* __restrict__ out)
{
    __shared__ __align__(16) float sO[8][2][4][64][4];   // 64 KB (two-pass merge)
    __shared__ float sM[8][2][16], sL[8][2][16];

    const int tid  = threadIdx.x;
    const int w    = tid >> 6;              // 0..7
    const int lane = tid & 63;
    const int r    = lane & 15;
    const int g    = lane >> 4;
    const int b    = blockIdx.x & 7;        // batch -> XCD pinning
    const int p    = blockIdx.x >> 3;       // 0..31: pair index
    const int qbL  = p * 32;
    const int qbH  = 2016 - p * 32;
    const int lastqL = qbL + 31;
    const int lastqH = qbH + 31;

    const unsigned short* Qbb = Qb + (size_t)b * 2048 * 64;
    const unsigned short* Kbb = Kb + (size_t)b * 2048 * 64;
    const unsigned short* Vtb = Vt + (size_t)b * 64 * 2048;

#define QBASE(qs) ((qs) < 2 ? (qbL + (qs) * 16) : (qbH + ((qs) - 2) * 16))

    bf16x8 qf[4][2];
#pragma unroll
    for (int qs = 0; qs < 4; ++qs)
#pragma unroll
        for (int h = 0; h < 2; ++h)
            qf[qs][h] = *(const bf16x8*)(Qbb + (size_t)(QBASE(qs) + r) * 64 + h * 32 + g * 8);

    f32x4 o[4][4];
#pragma unroll
    for (int qs = 0; qs < 4; ++qs)
#pragma unroll
        for (int i = 0; i < 4; ++i) o[qs][i] = (f32x4)0.0f;
    float m[4] = {-1e30f, -1e30f, -1e30f, -1e30f};
    float l[4] = {0.0f, 0.0f, 0.0f, 0.0f};

#define LOADK(K_, kv) do { \
        const int kra = (kv) + 8 * (r >> 2) + (r & 3); \
        K_[0] = *(const bf16x8*)(Kbb + (size_t)kra * 64 + g * 8); \
        K_[1] = *(const bf16x8*)(Kbb + (size_t)kra * 64 + 32 + g * 8); \
        K_[2] = *(const bf16x8*)(Kbb + (size_t)(kra + 4) * 64 + g * 8); \
        K_[3] = *(const bf16x8*)(Kbb + (size_t)(kra + 4) * 64 + 32 + g * 8); \
    } while (0)
#define LOADV(V_, kv) do { _Pragma("unroll") \
        for (int i = 0; i < 4; ++i) \
            V_[i] = *(const bf16x8*)(Vtb + (size_t)(i * 16 + r) * 2048 + (kv) + g * 8); \
    } while (0)

    // Full per-iteration body: QK^T (swapped), mask, defer-max, exp+pack, PV.
#define COMPUTE(K_, V_, kv0v) do { \
    const bool doLow = ((kv0v) <= lastqL); \
    f32x4 s0[4], s1[4]; \
    __builtin_amdgcn_s_setprio(1); \
    _Pragma("unroll") \
    for (int qs = 0; qs < 4; ++qs) { \
        s0[qs] = (f32x4)0.0f; s1[qs] = (f32x4)0.0f; \
        if (qs < 2 && !doLow) continue; \
        s0[qs] = __builtin_amdgcn_mfma_f32_16x16x32_bf16(K_[0], qf[qs][0], s0[qs], 0, 0, 0); \
        s0[qs] = __builtin_amdgcn_mfma_f32_16x16x32_bf16(K_[1], qf[qs][1], s0[qs], 0, 0, 0); \
        s1[qs] = __builtin_amdgcn_mfma_f32_16x16x32_bf16(K_[2], qf[qs][0], s1[qs], 0, 0, 0); \
        s1[qs] = __builtin_amdgcn_mfma_f32_16x16x32_bf16(K_[3], qf[qs][1], s1[qs], 0, 0, 0); \
    } \
    __builtin_amdgcn_s_setprio(0); \
    float lm[4] = {-1e30f, -1e30f, -1e30f, -1e30f}; \
    _Pragma("unroll") \
    for (int qs = 0; qs < 4; ++qs) { \
        if (qs < 2 && !doLow) continue; \
        const int q = QBASE(qs) + r; \
        if ((kv0v) + 31 > QBASE(qs)) { \
            _Pragma("unroll") \
            for (int j = 0; j < 4; ++j) { \
                if ((kv0v) + 8 * g + j > q)     s0[qs][j] = -1e30f; \
                if ((kv0v) + 8 * g + 4 + j > q) s1[qs][j] = -1e30f; \
            } \
        } \
        lm[qs] = fmaxf(fmaxf(fmaxf(s0[qs][0], s0[qs][1]), fmaxf(s0[qs][2], s0[qs][3])), \
                       fmaxf(fmaxf(s1[qs][0], s1[qs][1]), fmaxf(s1[qs][2], s1[qs][3]))); \
    } \
    if (!__all(lm[0] <= m[0] + 8.0f && lm[1] <= m[1] + 8.0f && \
               lm[2] <= m[2] + 8.0f && lm[3] <= m[3] + 8.0f)) { \
        _Pragma("unroll") \
        for (int qs = 0; qs < 4; ++qs) { \
            float t2 = fmaxf(lm[qs], __shfl_xor(lm[qs], 16)); \
            t2 = fmaxf(t2, __shfl_xor(t2, 32)); \
            const float mn = fmaxf(m[qs], t2); \
            const float alpha = __builtin_amdgcn_exp2f((m[qs] - mn) * LOG2E); \
            _Pragma("unroll") \
            for (int ht = 0; ht < 4; ++ht) o[qs][ht] *= alpha; \
            l[qs] *= alpha; \
            m[qs] = mn; \
        } \
    } \
    __builtin_amdgcn_s_setprio(1); \
    _Pragma("unroll") \
    for (int qs = 0; qs < 4; ++qs) { \
        if (qs < 2 && !doLow) continue; \
        float p0[4], p1[4]; \
        _Pragma("unroll") \
        for (int j = 0; j < 4; ++j) { \
            p0[j] = __builtin_amdgcn_exp2f((s0[qs][j] - m[qs]) * LOG2E); \
            p1[j] = __builtin_amdgcn_exp2f((s1[qs][j] - m[qs]) * LOG2E); \
            l[qs] += p0[j] + p1[j]; \
        } \
        i32x4 pw; \
        pw[0] = (int)pack2(p0[0], p0[1]); \
        pw[1] = (int)pack2(p0[2], p0[3]); \
        pw[2] = (int)pack2(p1[0], p1[1]); \
        pw[3] = (int)pack2(p1[2], p1[3]); \
        bf16x8 pfrag = __builtin_bit_cast(bf16x8, pw); \
        o[qs][0] = __builtin_amdgcn_mfma_f32_16x16x32_bf16(V_[0], pfrag, o[qs][0], 0, 0, 0); \
        o[qs][1] = __builtin_amdgcn_mfma_f32_16x16x32_bf16(V_[1], pfrag, o[qs][1], 0, 0, 0); \
        o[qs][2] = __builtin_amdgcn_mfma_f32_16x16x32_bf16(V_[2], pfrag, o[qs][2], 0, 0, 0); \
        o[qs][3] = __builtin_amdgcn_mfma_f32_16x16x32_bf16(V_[3], pfrag, o[qs][3], 0, 0, 0); \
    } \
    __builtin_amdgcn_s_setprio(0); \
    } while (0)

    bf16x8 K0[4], K1[4], VA[4];
    LOADK(K0, w * 32);
#pragma unroll 1
    for (int kv0 = w * 32; kv0 <= lastqH; kv0 += 512) {
        const int kvB = kv0 + 256;
        LOADV(VA, kv0);
        if (kvB <= lastqH) LOADK(K1, kvB);       // prefetch next iter's K
        COMPUTE(K0, VA, kv0);
        if (kvB <= lastqH) {
            const int kvC = kv0 + 512;
            LOADV(VA, kvB);
            if (kvC <= lastqH) LOADK(K0, kvC);   // prefetch next-next
            COMPUTE(K1, VA, kvB);
        }
    }

    // ---- merge 8 kv-split partials: two fully-static passes ------------------
#define MERGE_STORE(QS, Q2) do { \
        float lr = l[QS]; \
        lr += __shfl_xor(lr, 16); \
        lr += __shfl_xor(lr, 32); \
        if (g == 0) { sM[w][Q2][r] = m[QS]; sL[w][Q2][r] = lr; } \
        _Pragma("unroll") \
        for (int ht = 0; ht < 4; ++ht) *(f32x4*)&sO[w][Q2][ht][lane][0] = o[QS][ht]; \
    } while (0)

#define MERGE_WRITE(QBASE0) do { \
        const int q2 = w >> 2, ht = w & 3; \
        float M = sM[0][q2][r]; \
        _Pragma("unroll") \
        for (int wp = 1; wp < 8; ++wp) M = fmaxf(M, sM[wp][q2][r]); \
        float L = 0.0f; \
        float beta[8]; \
        _Pragma("unroll") \
        for (int wp = 0; wp < 8; ++wp) { \
            beta[wp] = __builtin_amdgcn_exp2f((sM[wp][q2][r] - M) * LOG2E); \
            L += beta[wp] * sL[wp][q2][r]; \
        } \
        f32x4 av = (f32x4)0.0f; \
        _Pragma("unroll") \
        for (int wp = 0; wp < 8; ++wp) { \
            f32x4 t = *(const f32x4*)&sO[wp][q2][ht][lane][0]; \
            av += t * beta[wp]; \
        } \
        const float inv = 1.0f / L; \
        const int qrow = (QBASE0) + q2 * 16 + r; \
        *(f32x4*)(out + ((size_t)b * 2048 + qrow) * 64 + ht * 16 + g * 4) = av * inv; \
    } while (0)

    MERGE_STORE(0, 0);
    MERGE_STORE(1, 1);
    __syncthreads();
    MERGE_WRITE(qbL);
    __syncthreads();
    MERGE_STORE(2, 0);
    MERGE_STORE(3, 1);
    __syncthreads();
    MERGE_WRITE(qbH);
}

extern "C" void kernel_launch(void* const* d_in, const int* in_sizes, int n_in,
                              void* d_out, int out_size, void* d_ws, size_t ws_size,
                              hipStream_t stream) {
    const float* x  = (const float*)d_in[0];
    const float* Wq = (const float*)d_in[1];
    const float* Wk = (const float*)d_in[2];
    const float* Wv = (const float*)d_in[3];
    float* out = (float*)d_out;

    unsigned short* Qb  = (unsigned short*)d_ws;                 // [8*2048][64]
    unsigned short* Kb  = Qb + (size_t)8 * 2048 * 64;            // [8*2048][64]
    unsigned short* Vt  = Kb + (size_t)8 * 2048 * 64;            // [8][64][2048]
    unsigned short* Wts = Vt + (size_t)8 * 64 * 2048;            // [16][1536][8]

    hipLaunchKernelGGL(wtrans_kernel, dim3(6, 16), dim3(256), 0, stream, Wq, Wk, Wv, Wts);
    hipLaunchKernelGGL(proj_kernel, dim3(512), dim3(256), 0, stream, x, Wts, Qb, Kb, Vt);
    hipLaunchKernelGGL(attn_kernel, dim3(256), dim3(512), 0, stream, Qb, Kb, Vt, out);
}

// Round 15
// 41.437 us; speedup vs baseline: 1.2019x; 1.2019x over previous
//
#include <hip/hip_runtime.h>
#include <hip/hip_bf16.h>

typedef __attribute__((ext_vector_type(8))) short bf16x8;
typedef __attribute__((ext_vector_type(4))) float f32x4;
typedef __attribute__((ext_vector_type(4))) int i32x4;

#define LOG2E 1.4426950408889634f

static __device__ __forceinline__ unsigned int f2bfu(float f) {
    return (unsigned int)__builtin_bit_cast(unsigned short, __float2bfloat16(f));
}
static __device__ __forceinline__ unsigned int pack2(float lo, float hi) {
    return (f2bfu(hi) << 16) | f2bfu(lo);
}
static __device__ __forceinline__ unsigned short f2bf(float f) {
    return __builtin_bit_cast(unsigned short, __float2bfloat16(f));
}

// ---------------- W prep: emit Wt in proj-staging-linear order, bf16 ----------
__global__ __launch_bounds__(256) void wtrans_kernel(
    const float* __restrict__ Wq, const float* __restrict__ Wk,
    const float* __restrict__ Wv, unsigned short* __restrict__ Wts)
{
    const int part = blockIdx.x;             // 0..5
    const int t    = blockIdx.y;             // 0..15
    const int c    = part * 256 + threadIdx.x;
    const int n    = c >> 3;
    const int mat  = n >> 6;
    const int nl   = n & 63;
    const int k0   = t * 64 + (c & 7) * 8;
    const float* W = (mat == 0) ? Wq : ((mat == 1) ? Wk : Wv);
    const float scale = (mat == 0) ? 0.03125f : 1.0f;
    unsigned int s[8];
#pragma unroll
    for (int j = 0; j < 8; ++j)
        s[j] = (unsigned int)f2bf(W[(size_t)(k0 + j) * 64 + nl] * scale);
    i32x4 pk;
    pk[0] = (int)(s[0] | (s[1] << 16));
    pk[1] = (int)(s[2] | (s[3] << 16));
    pk[2] = (int)(s[4] | (s[5] << 16));
    pk[3] = (int)(s[6] | (s[7] << 16));
    *(i32x4*)(Wts + (size_t)t * 12288 + (size_t)c * 8) = pk;
}

// ---------------- projection: x @ Wt^T -> Q (row-major), Kp/Vp (frag-blocked) -
// Each block = one 32-row tile = one kv tile. Epilogue stages K,V in LDS and
// writes fragment-blocked Kp[b][t][f][lane][8] / Vp[b][t][f][lane][8] so attn
// loads are fully coalesced (lane i reads base + i*16B, 1KB per instruction).
__global__ __launch_bounds__(256, 2) void proj_kernel(
    const float* __restrict__ x, const unsigned short* __restrict__ Wts,
    unsigned short* __restrict__ Qb, unsigned short* __restrict__ Kp,
    unsigned short* __restrict__ Vp)
{
    __shared__ __align__(16) unsigned short sA[2][32][72];    // [buf][m][k] bf16
    __shared__ __align__(16) unsigned short sB[2][192][72];   // [buf][n][k] bf16
    __shared__ __align__(16) unsigned short sVT[64][48];      // [h][tloc] V^T stage
    __shared__ __align__(16) unsigned short sK[32][72];       // [tloc][h] K stage

    const int tid  = threadIdx.x;
    const int w    = tid >> 6;
    const int wm   = w >> 1;
    const int wn   = w & 1;
    const int lane = tid & 63;
    const int r    = lane & 15;
    const int g    = lane >> 4;
    const int mbase = blockIdx.x * 32;

    const int arow = tid >> 3;
    const int acb  = (tid & 7) * 8;
    const float* xptr = x + (size_t)(mbase + arow) * 1024 + acb;

    f32x4 acc[6];
#pragma unroll
    for (int i = 0; i < 6; ++i) acc[i] = (f32x4)0.0f;

    float4 XAa0, XAa1, XAb0, XAb1;
    i32x4 BB[6];

#define LOADX(S0, S1, t_) do { \
        const float* xp = xptr + (size_t)(t_) * 64; \
        S0 = *(const float4*)(xp);  S1 = *(const float4*)(xp + 4); \
    } while (0)

#define LOADB(t_) do { \
        const unsigned short* wp = Wts + (size_t)(t_) * 12288 + (size_t)tid * 8; \
        _Pragma("unroll") \
        for (int i = 0; i < 6; ++i) BB[i] = *(const i32x4*)(wp + i * 2048); \
    } while (0)

#define STORESTEP(buf, S0, S1) do { \
        i32x4 pa0 = {(int)pack2(S0.x, S0.y), (int)pack2(S0.z, S0.w), \
                     (int)pack2(S1.x, S1.y), (int)pack2(S1.z, S1.w)}; \
        *(i32x4*)&sA[buf][arow][acb] = pa0; \
        _Pragma("unroll") \
        for (int i = 0; i < 6; ++i) { \
            const int c = tid + 256 * i; \
            *(i32x4*)&sB[buf][c >> 3][(c & 7) * 8] = BB[i]; \
        } \
    } while (0)

#define COMPSTEP(buf) do { \
        _Pragma("unroll") \
        for (int h = 0; h < 2; ++h) { \
            bf16x8 af = *(const bf16x8*)&sA[buf][wm * 16 + r][h * 32 + g * 8]; \
            _Pragma("unroll") \
            for (int nt = 0; nt < 6; ++nt) { \
                bf16x8 bfr = *(const bf16x8*)&sB[buf][(nt * 2 + wn) * 16 + r][h * 32 + g * 8]; \
                acc[nt] = __builtin_amdgcn_mfma_f32_16x16x32_bf16(af, bfr, acc[nt], 0, 0, 0); \
            } \
        } \
    } while (0)

    LOADX(XAa0, XAa1, 0);
    LOADX(XAb0, XAb1, 1);
    LOADB(0);
#pragma unroll 1
    for (int t = 0; t < 16; t += 2) {
        STORESTEP(0, XAa0, XAa1);
        __syncthreads();
        if (t + 2 < 16) LOADX(XAa0, XAa1, t + 2);
        LOADB(t + 1);
        COMPSTEP(0);
        STORESTEP(1, XAb0, XAb1);
        __syncthreads();
        if (t + 3 < 16) LOADX(XAb0, XAb1, t + 3);
        if (t + 2 < 16) LOADB(t + 2);
        COMPSTEP(1);
    }

    // ---- epilogue: Q direct; K,V staged in LDS then written frag-blocked ----
    const int row0  = mbase + wm * 16 + g * 4;   // global row
    const int lrow0 = wm * 16 + g * 4;           // row within this 32-row tile
#pragma unroll
    for (int nt = 0; nt < 6; ++nt) {
        const int ti  = nt * 2 + wn;
        const int mat = ti >> 2;
        const int col = (ti & 3) * 16 + r;
#pragma unroll
        for (int j = 0; j < 4; ++j) {
            const float v = acc[nt][j];
            if (mat == 0) {
                Qb[(size_t)(row0 + j) * 64 + col] = f2bf(v);   // scale folded in Wt
            } else if (mat == 1) {
                sK[lrow0 + j][col] = f2bf(v);
            } else {
                sVT[col][lrow0 + j] = f2bf(v);
            }
        }
    }
    __syncthreads();
    {
        const int bb = mbase >> 11;
        const int t  = (mbase & 2047) >> 5;      // kv-tile index 0..63
        const int f  = tid >> 6;                 // fragment 0..3
        const int r2 = lane & 15, g2 = lane >> 4;
        // K fragment f: row = perm(r)+ (f>>1)*4, cols = (f&1)*32 + g*8
        const int krow = 8 * (r2 >> 2) + (r2 & 3) + (f >> 1) * 4;
        const int kcol = (f & 1) * 32 + g2 * 8;
        *(i32x4*)(Kp + ((size_t)(bb * 64 + t) * 4 + f) * 512 + lane * 8)
            = *(const i32x4*)&sK[krow][kcol];
        // V fragment f (= ht): V^T[f*16+r][tile kv g*8..]
        *(i32x4*)(Vp + ((size_t)(bb * 64 + t) * 4 + f) * 512 + lane * 8)
            = *(const i32x4*)&sVT[f * 16 + r2][g2 * 8];
    }
}

// ---------------- causal flash attention -------------------------------------
// Balanced QBLK=64 (tiles p and 63-p), 8 waves kv-split mod 8, KV-step 32.
// K/V loads are coalesced 1KB bursts from frag-blocked Kp/Vp (bit-identical
// register contents to r13's gather loads). Static accumulator indexing.
__global__ __launch_bounds__(512, 2) void attn_kernel(
    const unsigned short* __restrict__ Qb, const unsigned short* __restrict__ Kp,
    const unsigned short* __restrict__ Vp, float* __restrict__ out)
{
    __shared__ __align__(16) float sO[8][2][4][64][4];   // 64 KB (two-pass merge)
    __shared__ float sM[8][2][16], sL[8][2][16];

    const int tid  = threadIdx.x;
    const int w    = tid >> 6;              // 0..7
    const int lane = tid & 63;
    const int r    = lane & 15;
    const int g    = lane >> 4;
    const int b    = blockIdx.x & 7;        // batch -> XCD pinning
    const int p    = blockIdx.x >> 3;       // 0..31: pair index
    const int qbL  = p * 32;
    const int qbH  = 2016 - p * 32;
    const int lastqL = qbL + 31;
    const int lastqH = qbH + 31;

    const unsigned short* Qbb = Qb + (size_t)b * 2048 * 64;
    const unsigned short* Kpb = Kp + (size_t)b * 64 * 2048;
    const unsigned short* Vpb = Vp + (size_t)b * 64 * 2048;

#define QBASE(qs) ((qs) < 2 ? (qbL + (qs) * 16) : (qbH + ((qs) - 2) * 16))

    bf16x8 qf[4][2];
#pragma unroll
    for (int qs = 0; qs < 4; ++qs)
#pragma unroll
        for (int h = 0; h < 2; ++h)
            qf[qs][h] = *(const bf16x8*)(Qbb + (size_t)(QBASE(qs) + r) * 64 + h * 32 + g * 8);

    f32x4 o[4][4];
#pragma unroll
    for (int qs = 0; qs < 4; ++qs)
#pragma unroll
        for (int i = 0; i < 4; ++i) o[qs][i] = (f32x4)0.0f;
    float m[4] = {-1e30f, -1e30f, -1e30f, -1e30f};
    float l[4] = {0.0f, 0.0f, 0.0f, 0.0f};

#define LOADK(K_, kvt) do { \
        const unsigned short* kp = Kpb + (size_t)(kvt) * 2048 + lane * 8; \
        K_[0] = *(const bf16x8*)(kp); \
        K_[1] = *(const bf16x8*)(kp + 512); \
        K_[2] = *(const bf16x8*)(kp + 1024); \
        K_[3] = *(const bf16x8*)(kp + 1536); \
    } while (0)
#define LOADV(V_, kvt) do { \
        const unsigned short* vp = Vpb + (size_t)(kvt) * 2048 + lane * 8; \
        _Pragma("unroll") \
        for (int i = 0; i < 4; ++i) V_[i] = *(const bf16x8*)(vp + i * 512); \
    } while (0)

    bf16x8 KA[4], VA[4];
#pragma unroll 1
    for (int kv0 = w * 32; kv0 <= lastqH; kv0 += 256) {
        const bool doLow = (kv0 <= lastqL);     // wave-uniform

        LOADK(KA, kv0 >> 5);
        LOADV(VA, kv0 >> 5);

        // ---- QK^T (swapped): s0[qs][j] = kv0+8g+j, s1[qs][j] = kv0+8g+4+j ----
        f32x4 s0[4], s1[4];
        __builtin_amdgcn_s_setprio(1);
#pragma unroll
        for (int qs = 0; qs < 4; ++qs) {
            s0[qs] = (f32x4)0.0f; s1[qs] = (f32x4)0.0f;
            if (qs < 2 && !doLow) continue;
            s0[qs] = __builtin_amdgcn_mfma_f32_16x16x32_bf16(KA[0], qf[qs][0], s0[qs], 0, 0, 0);
            s0[qs] = __builtin_amdgcn_mfma_f32_16x16x32_bf16(KA[1], qf[qs][1], s0[qs], 0, 0, 0);
            s1[qs] = __builtin_amdgcn_mfma_f32_16x16x32_bf16(KA[2], qf[qs][0], s1[qs], 0, 0, 0);
            s1[qs] = __builtin_amdgcn_mfma_f32_16x16x32_bf16(KA[3], qf[qs][1], s1[qs], 0, 0, 0);
        }
        __builtin_amdgcn_s_setprio(0);

        // ---- mask + lane-local max ----
        float lm[4] = {-1e30f, -1e30f, -1e30f, -1e30f};
#pragma unroll
        for (int qs = 0; qs < 4; ++qs) {
            if (qs < 2 && !doLow) continue;
            const int q = QBASE(qs) + r;
            if (kv0 + 31 > QBASE(qs)) {
#pragma unroll
                for (int j = 0; j < 4; ++j) {
                    if (kv0 + 8 * g + j > q)     s0[qs][j] = -1e30f;
                    if (kv0 + 8 * g + 4 + j > q) s1[qs][j] = -1e30f;
                }
            }
            lm[qs] = fmaxf(fmaxf(fmaxf(s0[qs][0], s0[qs][1]), fmaxf(s0[qs][2], s0[qs][3])),
                           fmaxf(fmaxf(s1[qs][0], s1[qs][1]), fmaxf(s1[qs][2], s1[qs][3])));
        }
        // defer-max: rescale only when some row's max grew past threshold
        if (!__all(lm[0] <= m[0] + 8.0f && lm[1] <= m[1] + 8.0f &&
                   lm[2] <= m[2] + 8.0f && lm[3] <= m[3] + 8.0f)) {
#pragma unroll
            for (int qs = 0; qs < 4; ++qs) {
                float t2 = fmaxf(lm[qs], __shfl_xor(lm[qs], 16));
                t2 = fmaxf(t2, __shfl_xor(t2, 32));
                const float mn = fmaxf(m[qs], t2);
                const float alpha = __builtin_amdgcn_exp2f((m[qs] - mn) * LOG2E);
#pragma unroll
                for (int ht = 0; ht < 4; ++ht) o[qs][ht] *= alpha;
                l[qs] *= alpha;
                m[qs] = mn;
            }
        }

        // ---- exp + pack + PV ----
        __builtin_amdgcn_s_setprio(1);
#pragma unroll
        for (int qs = 0; qs < 4; ++qs) {
            if (qs < 2 && !doLow) continue;
            float p0[4], p1[4];
#pragma unroll
            for (int j = 0; j < 4; ++j) {
                p0[j] = __builtin_amdgcn_exp2f((s0[qs][j] - m[qs]) * LOG2E);
                p1[j] = __builtin_amdgcn_exp2f((s1[qs][j] - m[qs]) * LOG2E);
                l[qs] += p0[j] + p1[j];
            }
            i32x4 pw;
            pw[0] = (int)pack2(p0[0], p0[1]);
            pw[1] = (int)pack2(p0[2], p0[3]);
            pw[2] = (int)pack2(p1[0], p1[1]);
            pw[3] = (int)pack2(p1[2], p1[3]);
            bf16x8 pfrag = __builtin_bit_cast(bf16x8, pw);
            o[qs][0] = __builtin_amdgcn_mfma_f32_16x16x32_bf16(VA[0], pfrag, o[qs][0], 0, 0, 0);
            o[qs][1] = __builtin_amdgcn_mfma_f32_16x16x32_bf16(VA[1], pfrag, o[qs][1], 0, 0, 0);
            o[qs][2] = __builtin_amdgcn_mfma_f32_16x16x32_bf16(VA[2], pfrag, o[qs][2], 0, 0, 0);
            o[qs][3] = __builtin_amdgcn_mfma_f32_16x16x32_bf16(VA[3], pfrag, o[qs][3], 0, 0, 0);
        }
        __builtin_amdgcn_s_setprio(0);
    }

    // ---- merge 8 kv-split partials: two fully-static passes ------------------
#define MERGE_STORE(QS, Q2) do { \
        float lr = l[QS]; \
        lr += __shfl_xor(lr, 16); \
        lr += __shfl_xor(lr, 32); \
        if (g == 0) { sM[w][Q2][r] = m[QS]; sL[w][Q2][r] = lr; } \
        _Pragma("unroll") \
        for (int ht = 0; ht < 4; ++ht) *(f32x4*)&sO[w][Q2][ht][lane][0] = o[QS][ht]; \
    } while (0)

#define MERGE_WRITE(QBASE0) do { \
        const int q2 = w >> 2, ht = w & 3; \
        float M = sM[0][q2][r]; \
        _Pragma("unroll") \
        for (int wp = 1; wp < 8; ++wp) M = fmaxf(M, sM[wp][q2][r]); \
        float L = 0.0f; \
        float beta[8]; \
        _Pragma("unroll") \
        for (int wp = 0; wp < 8; ++wp) { \
            beta[wp] = __builtin_amdgcn_exp2f((sM[wp][q2][r] - M) * LOG2E); \
            L += beta[wp] * sL[wp][q2][r]; \
        } \
        f32x4 av = (f32x4)0.0f; \
        _Pragma("unroll") \
        for (int wp = 0; wp < 8; ++wp) { \
            f32x4 t = *(const f32x4*)&sO[wp][q2][ht][lane][0]; \
            av += t * beta[wp]; \
        } \
        const float inv = 1.0f / L; \
        const int qrow = (QBASE0) + q2 * 16 + r; \
        *(f32x4*)(out + ((size_t)b * 2048 + qrow) * 64 + ht * 16 + g * 4) = av * inv; \
    } while (0)

    MERGE_STORE(0, 0);
    MERGE_STORE(1, 1);
    __syncthreads();
    MERGE_WRITE(qbL);
    __syncthreads();
    MERGE_STORE(2, 0);
    MERGE_STORE(3, 1);
    __syncthreads();
    MERGE_WRITE(qbH);
}

extern "C" void kernel_launch(void* const* d_in, const int* in_sizes, int n_in,
                              void* d_out, int out_size, void* d_ws, size_t ws_size,
                              hipStream_t stream) {
    const float* x  = (const float*)d_in[0];
    const float* Wq = (const float*)d_in[1];
    const float* Wk = (const float*)d_in[2];
    const float* Wv = (const float*)d_in[3];
    float* out = (float*)d_out;

    unsigned short* Qb  = (unsigned short*)d_ws;                 // [8*2048][64]
    unsigned short* Kp  = Qb + (size_t)8 * 2048 * 64;            // [8][64][4][64][8]
    unsigned short* Vp  = Kp + (size_t)8 * 64 * 2048;            // [8][64][4][64][8]
    unsigned short* Wts = Vp + (size_t)8 * 64 * 2048;            // [16][1536][8]

    hipLaunchKernelGGL(wtrans_kernel, dim3(6, 16), dim3(256), 0, stream, Wq, Wk, Wv, Wts);
    hipLaunchKernelGGL(proj_kernel, dim3(512), dim3(256), 0, stream, x, Wts, Qb, Kp, Vp);
    hipLaunchKernelGGL(attn_kernel, dim3(256), dim3(512), 0, stream, Qb, Kp, Vp, out);
}